// Round 2
// baseline (221.440 us; speedup 1.0000x reference)
//
#include <hip/hip_runtime.h>
#include <cstdint>
#include <cstddef>

typedef _Float16 f16x8 __attribute__((ext_vector_type(8)));
typedef float f32x4 __attribute__((ext_vector_type(4)));

#define NTOK 16384
#define DIMV 512
#define KCODE 4096

// output layout (float32): z_q_st | indices | vq_loss | perplexity
#define IDX_OFF (NTOK * DIMV)
#define LOSSO   (IDX_OFF + NTOK)
#define PERPO   (LOSSO + 1)

// workspace layout
static const size_t A2_OFF = 0;                                   // fp16 256*z   [NTOK][512]
static const size_t B2_OFF = A2_OFF + (size_t)NTOK * DIMV * 2;    // fp16 256*e   [KCODE][512]
static const size_t EN_OFF = B2_OFF + (size_t)KCODE * DIMV * 2;   // f32 C32 = np-pairwise ||e||^2
static const size_t RK_OFF = EN_OFF + (size_t)KCODE * 4;          // u32 [NTOK][16 tiles][2] top-2 keys
static const size_t CNT_OFF = RK_OFF + (size_t)NTOK * 32 * 4;     // u32 [KCODE]
static const size_t RLOSS_OFF = CNT_OFF + (size_t)KCODE * 4;      // f64 [NTOK] per-row loss

// fp32 square with contraction barrier (mimic numpy's separate multiply+add)
__device__ __forceinline__ float sqf(float v) {
    float p = v * v;
    asm volatile("" : "+v"(p));
    return p;
}

// numpy pairwise sum of squares of a 512-elem LDS row (verified r3-r8).
__device__ __forceinline__ float np_pairwise_sq(const float* xs, int t) {
    float accp = 0.0f;
    if (t < 32) {
        const float* blk = xs + (t >> 3) * 128;
        int j = t & 7;
        float rj = sqf(blk[j]);
#pragma unroll
        for (int tt = 1; tt < 16; ++tt) rj += sqf(blk[tt * 8 + j]);
        accp = rj;
    }
#pragma unroll
    for (int d = 1; d <= 16; d <<= 1) accp += __shfl_xor(accp, d, 64);
    return __shfl(accp, 0, 64);
}

// ---------------- fused prep: z->fp16, embed->fp16 + C32 + zero counts
__global__ void prep_k(const float* __restrict__ z, const float* __restrict__ e,
                       _Float16* __restrict__ A2, _Float16* __restrict__ B2,
                       float* __restrict__ C32, unsigned* __restrict__ counts) {
    __shared__ float es[4][512];
    const int b = blockIdx.x;
    if (b < 4096) {                       // z: 4 rows per block
        int t = b * 256 + threadIdx.x;
        int n = t >> 6;
        int dc = (t & 63) << 3;
        const float* zp = z + (size_t)n * DIMV + dc;
        float4 v0 = ((const float4*)zp)[0];
        float4 v1 = ((const float4*)zp)[1];
        float vs[8] = {v0.x, v0.y, v0.z, v0.w, v1.x, v1.y, v1.z, v1.w};
        f16x8 hi;
#pragma unroll
        for (int i = 0; i < 8; ++i) hi[i] = (_Float16)(vs[i] * 256.0f);
        *(f16x8*)(A2 + (size_t)n * DIMV + dc) = hi;
    } else {                              // embed: 4 rows per block, 1 wave/row
        const int wv = threadIdx.x >> 6, t = threadIdx.x & 63;
        const int k = (b - 4096) * 4 + wv;
        const float* ep = e + (size_t)k * DIMV + t * 8;
        float4 v0 = ((const float4*)ep)[0];
        float4 v1 = ((const float4*)ep)[1];
        ((float4*)es[wv])[t * 2] = v0;
        ((float4*)es[wv])[t * 2 + 1] = v1;
        float vs[8] = {v0.x, v0.y, v0.z, v0.w, v1.x, v1.y, v1.z, v1.w};
        f16x8 hi;
#pragma unroll
        for (int i = 0; i < 8; ++i) hi[i] = (_Float16)(vs[i] * 256.0f);
        *(f16x8*)(B2 + (size_t)k * DIMV + t * 8) = hi;
        float c = np_pairwise_sq(es[wv], t);
        if (t == 0) C32[k] = c;
        if (threadIdx.x < 4) counts[(b - 4096) * 4 + threadIdx.x] = 0u;
    }
}

// ---------------- async global->LDS 16B
typedef uint32_t __attribute__((address_space(1))) gas_u32;
typedef uint32_t __attribute__((address_space(3))) las_u32;
__device__ __forceinline__ void g2l16(const _Float16* g, _Float16* l) {
    __builtin_amdgcn_global_load_lds((const gas_u32*)(uintptr_t)g,
                                     (las_u32*)(uint32_t)(uintptr_t)l, 16, 0, 0);
}

__device__ __forceinline__ void top2_merge32(unsigned& k1, unsigned& k2,
                                             unsigned o1, unsigned o2) {
    unsigned n1 = k1 < o1 ? k1 : o1;
    unsigned mx = k1 < o1 ? o1 : k1;
    unsigned n2 = k2 < o2 ? k2 : o2;
    k1 = n1;
    k2 = mx < n2 ? mx : n2;
}

// DPP row_shr top-2 reduction stage (pure VALU, no DS pipe).
#define DPP_TOP2(CTRL)                                                                     \
    {                                                                                      \
        unsigned o1 = (unsigned)__builtin_amdgcn_update_dpp(-1, (int)k1, CTRL, 0xF, 0xF, false); \
        unsigned o2 = (unsigned)__builtin_amdgcn_update_dpp(-1, (int)k2, CTRL, 0xF, 0xF, false); \
        top2_merge32(k1, k2, o1, o2);                                                      \
    }

// ---------------- GEMM (K=512 fp16) + per-tile top-2.
// m201-faithful schedule: 256x256 tile, BK=64, 8 waves (2M x 4N), 128 KiB LDS.
// Per buffer (32768 f16): slots A0|B0|A1|B1, each a K-SLICE [256 rows][32 f16]
// (64 B rows -> lane(16q+r15) hits bank slot (r15&1)*16+q*4: all 32 banks
// uniform, 8 words/bank = minimum beats -> conflict-free, no swizzle needed;
// r1 measured 0 conflicts with identical row geometry).
// 4 phases per K-tile t (mh x ks quadrants), each:
//   {ds_read af[4] (+bf[4] at ks start)  <- ISSUED BEFORE BARRIER (latency
//    hidden under rendezvous);  stage one slice-half (2 x global_load_lds);
//    [counted vmcnt];  s_barrier;  lgkmcnt(0);  setprio(1); 16 MFMA; setprio(0);
//    [barrier2 only after ph2/ph4 where the next phase stages into a slot read
//     this phase]}.
// Stage FIFO (steady, tile t, c=t&1, n=c^1):
//   ph1 -> buf[n].A1 (t+1 ks1), ph2 -> buf[n].B1 (t+1 ks1),
//   ph3 -> buf[c].A0 (t+2 ks0; ks0 of c is dead after ph2),
//   ph4 -> buf[c].B0 (t+2 ks0).
// Waits (per-wave FIFO accounting, 2 loads/stage):
//   ph2: vmcnt(8) retires (t)A1,(t)B1 stages -> ks1 ready for ph3.   [t==7: 0]
//   ph4: vmcnt(8) retires (t+1)A0,(t+1)B0  -> ks0 ready for t+1 ph1. [t==6: 4]
// 8 loads stay in flight after every steady wait -- never drained (T3+T4).
#define PHASE(MH, KS, LOADB, STAGE, WAIT, BAR2)                                   \
    {                                                                             \
        const int sb = bb + (KS)*16384;                                           \
        f16x8 af[4];                                                              \
        _Pragma("unroll") for (int i = 0; i < 4; ++i)                             \
            af[i] = *(const f16x8*)&L[sb + aBase + (MH)*2048 + i * 512];          \
        if (LOADB) {                                                              \
            _Pragma("unroll") for (int j = 0; j < 4; ++j)                         \
                bf[j] = *(const f16x8*)&L[sb + bBase + j * 512];                  \
        }                                                                         \
        STAGE;                                                                    \
        WAIT;                                                                     \
        __builtin_amdgcn_s_barrier();                                             \
        asm volatile("s_waitcnt lgkmcnt(0)" ::: "memory");                        \
        __builtin_amdgcn_sched_barrier(0);                                        \
        __builtin_amdgcn_s_setprio(1);                                            \
        _Pragma("unroll") for (int i = 0; i < 4; ++i)                             \
            _Pragma("unroll") for (int j = 0; j < 4; ++j)                         \
                acc[(MH)*4 + i][j] = __builtin_amdgcn_mfma_f32_16x16x32_f16(      \
                    af[i], bf[j], acc[(MH)*4 + i][j], 0, 0, 0);                   \
        __builtin_amdgcn_s_setprio(0);                                            \
        if (BAR2) __builtin_amdgcn_s_barrier();                                   \
    }

__global__ __launch_bounds__(512, 2) void gemm_top2_k(
    const _Float16* __restrict__ A2, const _Float16* __restrict__ B2,
    const float* __restrict__ C32, unsigned* __restrict__ rk2) {
    __shared__ __align__(16) _Float16 L[65536];   // 128 KiB: 2 bufs x 4 slices

    const int nt = blockIdx.x;     // 16 code tiles of 256
    const int mt = blockIdx.y;     // 64 row tiles of 256
    const int tid = threadIdx.x;
    const int w = tid >> 6, l = tid & 63;
    const int wm = w >> 2, wn = w & 3;            // 2 (M) x 4 (N) wave grid
    const int lane15 = l & 15, q = l >> 4;

    // staging: lane l covers LDS f16 [w*1024 + r*512 + l*8 .. +7] of a slice
    //   -> row = w*32 + r*16 + (l>>2), k_in_slice = (l&3)*8  (LDS dest linear,
    //      wave-uniform base; global source per-lane)
    const int lr = l >> 2, lk = (l & 3) * 8;
    const _Float16* aG = A2 + (size_t)(mt * 256 + w * 32 + lr) * DIMV + lk;
    const _Float16* bG = B2 + (size_t)(nt * 256 + w * 32 + lr) * DIMV + lk;

    auto stA = [&](int dst, int kt, int ks) {
        const _Float16* s = aG + kt * 64 + ks * 32;
        _Float16* d = &L[dst + w * 1024];
        g2l16(s, d);
        g2l16(s + 16 * DIMV, d + 512);
    };
    auto stB = [&](int dst, int kt, int ks) {
        const _Float16* s = bG + kt * 64 + ks * 32;
        _Float16* d = &L[dst + w * 1024];
        g2l16(s, d);
        g2l16(s + 16 * DIMV, d + 512);
    };

    // fragment-read lane offsets within a slice (row stride 32 f16)
    const int aBase = (wm * 128 + lane15) * 32 + q * 8;          // + MH*2048 + i*512
    const int bBase = 8192 + (wn * 64 + lane15) * 32 + q * 8;    // + j*512

    f32x4 acc[8][4] = {};
    f16x8 bf[4];

    // prologue FIFO: t0.A0 t0.B0 t0.A1 t0.B1 t1.A0 t1.B0 (12 loads);
    // vmcnt(8) retires t0.A0+t0.B0; barrier for cross-wave visibility.
    stA(0, 0, 0);          stB(8192, 0, 0);
    stA(16384, 0, 1);      stB(24576, 0, 1);
    stA(32768, 1, 0);      stB(32768 + 8192, 1, 0);
    asm volatile("s_waitcnt vmcnt(8)" ::: "memory");
    __builtin_amdgcn_s_barrier();

    for (int t = 0; t < 8; ++t) {
        const int bb = (t & 1) << 15;
        const int nb = bb ^ 32768;
        // ph1 (mh0,ks0): stage t+1 A-ks1 -> buf[n].A1
        PHASE(0, 0, true,
              { if (t < 7) stA(nb + 16384, t + 1, 1); },
              {}, false)
        // ph2 (mh1,ks0): stage t+1 B-ks1 -> buf[n].B1; wait for this tile's ks1
        PHASE(1, 0, false,
              { if (t < 7) stB(nb + 24576, t + 1, 1); },
              { if (t < 7) { asm volatile("s_waitcnt vmcnt(8)" ::: "memory"); }
                else       { asm volatile("s_waitcnt vmcnt(0)" ::: "memory"); } },
              true)
        // ph3 (mh0,ks1): stage t+2 A-ks0 -> buf[c].A0 (dead after ph2)
        PHASE(0, 1, true,
              { if (t < 6) stA(bb, t + 2, 0); },
              {}, false)
        // ph4 (mh1,ks1): stage t+2 B-ks0 -> buf[c].B0; wait for t+1's ks0
        PHASE(1, 1, false,
              { if (t < 6) stB(bb + 8192, t + 2, 0); },
              { if (t < 6)      { asm volatile("s_waitcnt vmcnt(8)" ::: "memory"); }
                else if (t == 6){ asm volatile("s_waitcnt vmcnt(4)" ::: "memory"); } },
              true)
    }

    // epilogue: dist = 65536*C32 - 2*acc + BIAS (4e6 > |range|): positive => raw
    // IEEE bits monotone; truncate to 24 bits, pack tile-col in low byte.
    unsigned* lk32 = (unsigned*)L;                   // [256 rows][stride 10]
    const int colL = wn * 64 + lane15;               // 0..255 within tile
    float envals[4];
#pragma unroll
    for (int j = 0; j < 4; ++j) envals[j] = C32[nt * 256 + colL + j * 16] * 65536.0f + 4.0e6f;

#pragma unroll
    for (int mf = 0; mf < 8; ++mf) {
#pragma unroll
        for (int rr = 0; rr < 4; ++rr) {
            unsigned k1 = 0xFFFFFFFFu, k2 = 0xFFFFFFFFu;
#pragma unroll
            for (int j = 0; j < 4; ++j) {
                float dist = envals[j] - 2.0f * acc[mf][j][rr];
                unsigned key = (__float_as_uint(dist) & 0xFFFFFF00u) | (unsigned)(colL + j * 16);
                if (key < k1) { k2 = k1; k1 = key; } else if (key < k2) k2 = key;
            }
            DPP_TOP2(0x118)   // row_shr:8
            DPP_TOP2(0x114)   // row_shr:4
            DPP_TOP2(0x112)   // row_shr:2
            DPP_TOP2(0x111)   // row_shr:1  -> LANE 15 of each 16 has row top-2
            if (lane15 == 15) {
                int rl = wm * 128 + mf * 16 + q * 4 + rr;
                lk32[rl * 10 + wn * 2]     = k1;
                lk32[rl * 10 + wn * 2 + 1] = k2;
            }
        }
    }
    __syncthreads();
    if (tid < 256) {
        unsigned a1 = lk32[tid * 10], a2 = lk32[tid * 10 + 1];
#pragma unroll
        for (int p = 1; p < 4; ++p)
            top2_merge32(a1, a2, lk32[tid * 10 + p * 2], lk32[tid * 10 + p * 2 + 1]);
        size_t base = (size_t)(mt * 256 + tid) * 32 + nt * 2;
        rk2[base] = a1;
        rk2[base + 1] = a2;
    }
}

// ---------------- refine: np-fp32-semantics over approx-top-4 of 32 candidates;
// winner z_q via LDS broadcast from the winning group's registers. NO fences.
__global__ __launch_bounds__(256) void refine_k(
    const unsigned* __restrict__ rk2,
    const float* __restrict__ embed, const float* __restrict__ z,
    const float* __restrict__ C32,
    float* __restrict__ out, unsigned* __restrict__ counts,
    double* __restrict__ rloss) {
    __shared__ float zs[4][512];
    __shared__ float zqs[4][512];
    const int wv = threadIdx.x >> 6, t = threadIdx.x & 63;
    const int r = blockIdx.x * 4 + wv;
    const float4* zp = (const float4*)(z + (size_t)r * DIMV);
    float4 za = zp[t * 2], zb = zp[t * 2 + 1];
    ((float4*)zs[wv])[t * 2] = za;
    ((float4*)zs[wv])[t * 2 + 1] = zb;
    __syncthreads();

    // np-exact A = np.sum(z*z, axis=1)
    float A32 = np_pairwise_sq(zs[wv], t);

    // rebuild unique u64 work keys (biased-dist24 | global col) from u32 keys
    unsigned long long key = ~0ull;
    if (t < 32) {
        unsigned kraw = rk2[(size_t)r * 32 + t];
        unsigned col = (unsigned)(t >> 1) * 256u + (kraw & 255u);
        key = ((unsigned long long)(kraw & 0xFFFFFF00u) << 32) | col;
    }

    // extract approx top-4; 16-lane group g keeps candidate #g
    const int g = t >> 4, j = t & 15;
    unsigned mycand = 0;
#pragma unroll
    for (int c = 0; c < 4; ++c) {
        unsigned long long m = key;
#pragma unroll
        for (int d = 1; d < 64; d <<= 1) {
            unsigned long long o = __shfl_xor(m, d, 64);
            m = o < m ? o : m;
        }
        if (c == g) mycand = (unsigned)(m & 0xFFFFFFFFull);
        if (key == m) key = ~0ull;   // keys unique (global col in low bits)
    }

    // parallel scoring: group g computes B = z . e_mycand in fp64; keep e vals
    const float4* ep = (const float4*)(embed + (size_t)mycand * DIMV);
    float4 ev[8];
    double s = 0.0;
#pragma unroll
    for (int it = 0; it < 8; ++it) {
        float4 e4 = ep[j + it * 16];
        ev[it] = e4;
        float4 z4 = ((const float4*)zs[wv])[j + it * 16];
        s += (double)z4.x * e4.x + (double)z4.y * e4.y +
             (double)z4.z * e4.z + (double)z4.w * e4.w;
    }
#pragma unroll
    for (int d = 1; d < 16; d <<= 1) s += __shfl_xor(s, d, 64);   // group sum

    // np rounding grid: d = fl(fl(A - 2B) + C)
    float Bf = (float)s;
    float d32 = (A32 - 2.0f * Bf) + C32[mycand];
    unsigned u = __float_as_uint(d32);
    u = (u & 0x80000000u) ? ~u : (u | 0x80000000u);
    unsigned long long dk = ((unsigned long long)u << 32) | mycand;
#pragma unroll
    for (int d = 16; d < 64; d <<= 1) {                           // cross-group argmin
        unsigned long long o = __shfl_xor(dk, d, 64);
        dk = o < dk ? o : dk;
    }
    const unsigned ibest = (unsigned)(dk & 0xFFFFFFFFull);

    // winner broadcast: winning group's registers -> LDS (candidates unique,
    // exactly one group matches)
    if (mycand == ibest) {
#pragma unroll
        for (int it = 0; it < 8; ++it) ((float4*)zqs[wv])[j + it * 16] = ev[it];
    }
    __syncthreads();

    float4 wa = ((const float4*)zqs[wv])[t * 2];
    float4 wb = ((const float4*)zqs[wv])[t * 2 + 1];
    float4* op = (float4*)(out + (size_t)r * DIMV);
    op[t * 2] = wa;
    op[t * 2 + 1] = wb;
    double dx0 = (double)za.x - wa.x, dx1 = (double)za.y - wa.y;
    double dx2 = (double)za.z - wa.z, dx3 = (double)za.w - wa.w;
    double dx4 = (double)zb.x - wb.x, dx5 = (double)zb.y - wb.y;
    double dx6 = (double)zb.z - wb.z, dx7 = (double)zb.w - wb.w;
    double ls = dx0 * dx0 + dx1 * dx1 + dx2 * dx2 + dx3 * dx3 +
                dx4 * dx4 + dx5 * dx5 + dx6 * dx6 + dx7 * dx7;
#pragma unroll
    for (int d = 1; d < 64; d <<= 1) ls += __shfl_xor(ls, d, 64);
    if (t == 0) {
        out[IDX_OFF + r] = (float)ibest;
        rloss[r] = ls;
        atomicAdd(&counts[ibest], 1u);
    }
}

// ---------------- scalars: vq_loss (reduce rloss) + perplexity. Separate
// dispatch: the kernel boundary is the (free) device-scope coherence point —
// r9 showed per-block __threadfence costs ~500us here.
__global__ __launch_bounds__(1024) void scalars_k(
    const unsigned* __restrict__ counts,
    const double* __restrict__ rloss, float* __restrict__ out) {
    int t = threadIdx.x;   // 1024
    double ls = 0.0;
    for (int i = t; i < NTOK; i += 1024) ls += rloss[i];
#pragma unroll
    for (int d = 1; d < 64; d <<= 1) ls += __shfl_xor(ls, d, 64);
    float s = 0.0f;
    for (int i = t; i < KCODE; i += 1024) {
        float p = (float)counts[i] * (1.0f / (float)NTOK);
        s += p * logf(p + 1e-10f);
    }
#pragma unroll
    for (int d = 1; d < 64; d <<= 1) s += __shfl_xor(s, d, 64);
    __shared__ float red[16];
    __shared__ double redd[16];
    if ((t & 63) == 0) { red[t >> 6] = s; redd[t >> 6] = ls; }
    __syncthreads();
    if (t == 0) {
        float stot = 0.0f;
        double ltot = 0.0;
#pragma unroll
        for (int i = 0; i < 16; ++i) { stot += red[i]; ltot += redd[i]; }
        out[PERPO] = expf(-stot);
        out[LOSSO] = 0.25f * (float)(ltot * (1.0 / (double)(NTOK * DIMV)));
    }
}

extern "C" void kernel_launch(void* const* d_in, const int* in_sizes, int n_in,
                              void* d_out, int out_size, void* d_ws, size_t ws_size,
                              hipStream_t stream) {
    const float* z     = (const float*)d_in[0];
    const float* embed = (const float*)d_in[1];
    float* out = (float*)d_out;
    char* ws = (char*)d_ws;

    _Float16* A2 = (_Float16*)(ws + A2_OFF);
    _Float16* B2 = (_Float16*)(ws + B2_OFF);
    float* C32 = (float*)(ws + EN_OFF);
    unsigned* rk2 = (unsigned*)(ws + RK_OFF);
    unsigned* counts = (unsigned*)(ws + CNT_OFF);
    double* rloss = (double*)(ws + RLOSS_OFF);

    prep_k<<<5120, 256, 0, stream>>>(z, embed, A2, B2, C32, counts);
    gemm_top2_k<<<dim3(16, 64), 512, 0, stream>>>(A2, B2, C32, rk2);
    refine_k<<<NTOK / 4, 256, 0, stream>>>(rk2, embed, z, C32, out, counts, rloss);
    scalars_k<<<1, 1024, 0, stream>>>(counts, rloss, out);
}

// Round 3
// 218.619 us; speedup vs baseline: 1.0129x; 1.0129x over previous
//
#include <hip/hip_runtime.h>
#include <cstdint>
#include <cstddef>

typedef _Float16 f16x8 __attribute__((ext_vector_type(8)));
typedef float f32x4 __attribute__((ext_vector_type(4)));

#define NTOK 16384
#define DIMV 512
#define KCODE 4096

// output layout (float32): z_q_st | indices | vq_loss | perplexity
#define IDX_OFF (NTOK * DIMV)
#define LOSSO   (IDX_OFF + NTOK)
#define PERPO   (LOSSO + 1)

// workspace layout
static const size_t A2_OFF = 0;                                   // fp16 256*z   [NTOK][512]
static const size_t B2_OFF = A2_OFF + (size_t)NTOK * DIMV * 2;    // fp16 256*e   [KCODE][512]
static const size_t EN_OFF = B2_OFF + (size_t)KCODE * DIMV * 2;   // f32 C32 = np-pairwise ||e||^2
static const size_t RK_OFF = EN_OFF + (size_t)KCODE * 4;          // u32 [NTOK][16 tiles][2] top-2 keys
static const size_t CNT_OFF = RK_OFF + (size_t)NTOK * 32 * 4;     // u32 [KCODE]
static const size_t RLOSS_OFF = CNT_OFF + (size_t)KCODE * 4;      // f64 [NTOK] per-row loss

// fp32 square with contraction barrier (mimic numpy's separate multiply+add)
__device__ __forceinline__ float sqf(float v) {
    float p = v * v;
    asm volatile("" : "+v"(p));
    return p;
}

// numpy pairwise sum of squares of a 512-elem LDS row (verified r3-r8).
__device__ __forceinline__ float np_pairwise_sq(const float* xs, int t) {
    float accp = 0.0f;
    if (t < 32) {
        const float* blk = xs + (t >> 3) * 128;
        int j = t & 7;
        float rj = sqf(blk[j]);
#pragma unroll
        for (int tt = 1; tt < 16; ++tt) rj += sqf(blk[tt * 8 + j]);
        accp = rj;
    }
#pragma unroll
    for (int d = 1; d <= 16; d <<= 1) accp += __shfl_xor(accp, d, 64);
    return __shfl(accp, 0, 64);
}

// ---------------- fused prep: z->fp16, embed->fp16 + C32 + zero counts
__global__ void prep_k(const float* __restrict__ z, const float* __restrict__ e,
                       _Float16* __restrict__ A2, _Float16* __restrict__ B2,
                       float* __restrict__ C32, unsigned* __restrict__ counts) {
    __shared__ float es[4][512];
    const int b = blockIdx.x;
    if (b < 4096) {                       // z: 4 rows per block
        int t = b * 256 + threadIdx.x;
        int n = t >> 6;
        int dc = (t & 63) << 3;
        const float* zp = z + (size_t)n * DIMV + dc;
        float4 v0 = ((const float4*)zp)[0];
        float4 v1 = ((const float4*)zp)[1];
        float vs[8] = {v0.x, v0.y, v0.z, v0.w, v1.x, v1.y, v1.z, v1.w};
        f16x8 hi;
#pragma unroll
        for (int i = 0; i < 8; ++i) hi[i] = (_Float16)(vs[i] * 256.0f);
        *(f16x8*)(A2 + (size_t)n * DIMV + dc) = hi;
    } else {                              // embed: 4 rows per block, 1 wave/row
        const int wv = threadIdx.x >> 6, t = threadIdx.x & 63;
        const int k = (b - 4096) * 4 + wv;
        const float* ep = e + (size_t)k * DIMV + t * 8;
        float4 v0 = ((const float4*)ep)[0];
        float4 v1 = ((const float4*)ep)[1];
        ((float4*)es[wv])[t * 2] = v0;
        ((float4*)es[wv])[t * 2 + 1] = v1;
        float vs[8] = {v0.x, v0.y, v0.z, v0.w, v1.x, v1.y, v1.z, v1.w};
        f16x8 hi;
#pragma unroll
        for (int i = 0; i < 8; ++i) hi[i] = (_Float16)(vs[i] * 256.0f);
        *(f16x8*)(B2 + (size_t)k * DIMV + t * 8) = hi;
        float c = np_pairwise_sq(es[wv], t);
        if (t == 0) C32[k] = c;
        if (threadIdx.x < 4) counts[(b - 4096) * 4 + threadIdx.x] = 0u;
    }
}

// ---------------- async global->LDS 16B
typedef uint32_t __attribute__((address_space(1))) gas_u32;
typedef uint32_t __attribute__((address_space(3))) las_u32;
__device__ __forceinline__ void g2l16(const _Float16* g, _Float16* l) {
    __builtin_amdgcn_global_load_lds((const gas_u32*)(uintptr_t)g,
                                     (las_u32*)(uint32_t)(uintptr_t)l, 16, 0, 0);
}

__device__ __forceinline__ void top2_merge32(unsigned& k1, unsigned& k2,
                                             unsigned o1, unsigned o2) {
    unsigned n1 = k1 < o1 ? k1 : o1;
    unsigned mx = k1 < o1 ? o1 : k1;
    unsigned n2 = k2 < o2 ? k2 : o2;
    k1 = n1;
    k2 = mx < n2 ? mx : n2;
}

// DPP row_shr top-2 reduction stage (pure VALU, no DS pipe).
#define DPP_TOP2(CTRL)                                                                     \
    {                                                                                      \
        unsigned o1 = (unsigned)__builtin_amdgcn_update_dpp(-1, (int)k1, CTRL, 0xF, 0xF, false); \
        unsigned o2 = (unsigned)__builtin_amdgcn_update_dpp(-1, (int)k2, CTRL, 0xF, 0xF, false); \
        top2_merge32(k1, k2, o1, o2);                                                      \
    }

// ---------------- GEMM (K=512 fp16) + per-tile top-2.
// 256x256 tile, BK=64 split in 2 K-slices, 8 waves (2M x 4N), 128 KiB LDS.
// Buffer (32768 f16) = [ks0: A0|B0][ks1: A1|B1], slice = [256 rows][32 f16].
// SWIZZLE (r1-verified, 0 conflicts): LDS[row][slot] holds global k-chunk
// slot ^ ((row>>1)&3). Realized by pre-swizzling the GLOBAL source (staging
// dest stays linear, as global_load_lds requires); fragment reads use
// slot8 = (q ^ ((lane15>>1)&3))*8. Quarter-wave bank check: 16 lanes spread
// over all 8 four-bank groups, 2/bank = free. (r2's unswizzled layout was an
// 8-way conflict: 6.29M cycles -- fixed here.)
// Phase = { ds_read frags; stage one slice (2 x global_load_lds);
//           [counted vmcnt]; [phase-barrier: ph2/ph4 only]; lgkmcnt(0);
//           setprio(1); 16 MFMA; setprio(0); [BAR2: ph2/ph4 only] }.
// 4 barriers/tile. Hazard chains (each verified):
//  - ph1/ph3 read visibility: fenced by prior ph4/ph2 phase-barrier (sits
//    right after the vmcnt retire of exactly those slices).
//  - ph1/ph3 stage WAR safety: target slice's last readers completed at their
//    lgkmcnt(0), which precedes the BAR2 the stage is issued after.
// Stage FIFO (tile t, c=t&1, n=c^1): ph1->(t+1)A1, ph2->(t+1)B1,
// ph3->(t+2)A0, ph4->(t+2)B0 (ks0 of buf[c] dead after ph2).
// Waits: ph2 vmcnt(8) retires (t)A1,(t)B1 [t==7: 0]; ph4 vmcnt(8) retires
// (t+1)A0,(t+1)B0 [t==6: 4]. 8 loads stay in flight -- never drained (T3+T4).
#define PHASE(MH, KS, LOADB, STAGE, WAIT, PBAR, BAR2)                             \
    {                                                                             \
        const int sb = bb + (KS)*16384;                                           \
        f16x8 af[4];                                                              \
        _Pragma("unroll") for (int i = 0; i < 4; ++i)                             \
            af[i] = *(const f16x8*)&L[sb + aBase + (MH)*2048 + i * 512];          \
        if (LOADB) {                                                              \
            _Pragma("unroll") for (int j = 0; j < 4; ++j)                         \
                bf[j] = *(const f16x8*)&L[sb + bBase + j * 512];                  \
        }                                                                         \
        STAGE;                                                                    \
        WAIT;                                                                     \
        if (PBAR) __builtin_amdgcn_s_barrier();                                   \
        asm volatile("s_waitcnt lgkmcnt(0)" ::: "memory");                        \
        __builtin_amdgcn_sched_barrier(0);                                        \
        __builtin_amdgcn_s_setprio(1);                                            \
        _Pragma("unroll") for (int i = 0; i < 4; ++i)                             \
            _Pragma("unroll") for (int j = 0; j < 4; ++j)                         \
                acc[(MH)*4 + i][j] = __builtin_amdgcn_mfma_f32_16x16x32_f16(      \
                    af[i], bf[j], acc[(MH)*4 + i][j], 0, 0, 0);                   \
        __builtin_amdgcn_s_setprio(0);                                            \
        if (BAR2) __builtin_amdgcn_s_barrier();                                   \
    }

__global__ __launch_bounds__(512, 2) void gemm_top2_k(
    const _Float16* __restrict__ A2, const _Float16* __restrict__ B2,
    const float* __restrict__ C32, unsigned* __restrict__ rk2) {
    __shared__ __align__(16) _Float16 L[65536];   // 128 KiB: 2 bufs x 4 slices

    const int nt = blockIdx.x;     // 16 code tiles of 256
    const int mt = blockIdx.y;     // 64 row tiles of 256
    const int tid = threadIdx.x;
    const int w = tid >> 6, l = tid & 63;
    const int wm = w >> 2, wn = w & 3;            // 2 (M) x 4 (N) wave grid
    const int lane15 = l & 15, q = l >> 4;

    // staging: lane l -> LDS f16 [base + w*1024 + l*8 .. +7] of a slice,
    // i.e. row = w*32 + (l>>2) (+16 for 2nd load), slot = l&3. Source chunk
    // pre-swizzled: cswz = (l&3) ^ ((l>>3)&3)  ( == slot ^ ((row>>1)&3) ).
    const int lr = l >> 2;
    const int cswz = ((l & 3) ^ ((l >> 3) & 3)) * 8;
    const _Float16* aG = A2 + (size_t)(mt * 256 + w * 32 + lr) * DIMV + cswz;
    const _Float16* bG = B2 + (size_t)(nt * 256 + w * 32 + lr) * DIMV + cswz;

    auto stA = [&](int dst, int kt, int ks) {
        const _Float16* s = aG + kt * 64 + ks * 32;
        _Float16* d = &L[dst + w * 1024];
        g2l16(s, d);
        g2l16(s + 16 * DIMV, d + 512);
    };
    auto stB = [&](int dst, int kt, int ks) {
        const _Float16* s = bG + kt * 64 + ks * 32;
        _Float16* d = &L[dst + w * 1024];
        g2l16(s, d);
        g2l16(s + 16 * DIMV, d + 512);
    };

    // fragment-read lane offsets within a slice (row stride 32 f16, swizzled
    // slot; all fragment row bases are 16-aligned so the swizzle term is
    // (lane15>>1)&3 uniformly)
    const int slot8 = (q ^ ((lane15 >> 1) & 3)) * 8;
    const int aBase = (wm * 128 + lane15) * 32 + slot8;          // + MH*2048 + i*512
    const int bBase = 8192 + (wn * 64 + lane15) * 32 + slot8;    // + j*512

    f32x4 acc[8][4] = {};
    f16x8 bf[4];

    // prologue FIFO: t0.A0 t0.B0 t0.A1 t0.B1 t1.A0 t1.B0 (12 loads);
    // vmcnt(8) retires t0.A0+t0.B0; barrier for cross-wave visibility.
    stA(0, 0, 0);          stB(8192, 0, 0);
    stA(16384, 0, 1);      stB(24576, 0, 1);
    stA(32768, 1, 0);      stB(32768 + 8192, 1, 0);
    asm volatile("s_waitcnt vmcnt(8)" ::: "memory");
    __builtin_amdgcn_s_barrier();

    for (int t = 0; t < 8; ++t) {
        const int bb = (t & 1) << 15;
        const int nb = bb ^ 32768;
        // ph1 (mh0,ks0): stage t+1 A-ks1 -> buf[n].A1
        PHASE(0, 0, true,
              { if (t < 7) stA(nb + 16384, t + 1, 1); },
              {}, false, false)
        // ph2 (mh1,ks0): stage t+1 B-ks1 -> buf[n].B1; wait for this tile's ks1
        PHASE(1, 0, false,
              { if (t < 7) stB(nb + 24576, t + 1, 1); },
              { if (t < 7) { asm volatile("s_waitcnt vmcnt(8)" ::: "memory"); }
                else       { asm volatile("s_waitcnt vmcnt(0)" ::: "memory"); } },
              true, true)
        // ph3 (mh0,ks1): stage t+2 A-ks0 -> buf[c].A0 (dead after ph2)
        PHASE(0, 1, true,
              { if (t < 6) stA(bb, t + 2, 0); },
              {}, false, false)
        // ph4 (mh1,ks1): stage t+2 B-ks0 -> buf[c].B0; wait for t+1's ks0
        PHASE(1, 1, false,
              { if (t < 6) stB(bb + 8192, t + 2, 0); },
              { if (t < 6)      { asm volatile("s_waitcnt vmcnt(8)" ::: "memory"); }
                else if (t == 6){ asm volatile("s_waitcnt vmcnt(4)" ::: "memory"); } },
              true, true)
    }

    // epilogue: dist = 65536*C32 - 2*acc + BIAS (4e6 > |range|): positive => raw
    // IEEE bits monotone; truncate to 24 bits, pack tile-col in low byte.
    unsigned* lk32 = (unsigned*)L;                   // [256 rows][stride 10]
    const int colL = wn * 64 + lane15;               // 0..255 within tile
    float envals[4];
#pragma unroll
    for (int j = 0; j < 4; ++j) envals[j] = C32[nt * 256 + colL + j * 16] * 65536.0f + 4.0e6f;

#pragma unroll
    for (int mf = 0; mf < 8; ++mf) {
#pragma unroll
        for (int rr = 0; rr < 4; ++rr) {
            unsigned k1 = 0xFFFFFFFFu, k2 = 0xFFFFFFFFu;
#pragma unroll
            for (int j = 0; j < 4; ++j) {
                float dist = envals[j] - 2.0f * acc[mf][j][rr];
                unsigned key = (__float_as_uint(dist) & 0xFFFFFF00u) | (unsigned)(colL + j * 16);
                if (key < k1) { k2 = k1; k1 = key; } else if (key < k2) k2 = key;
            }
            DPP_TOP2(0x118)   // row_shr:8
            DPP_TOP2(0x114)   // row_shr:4
            DPP_TOP2(0x112)   // row_shr:2
            DPP_TOP2(0x111)   // row_shr:1  -> LANE 15 of each 16 has row top-2
            if (lane15 == 15) {
                int rl = wm * 128 + mf * 16 + q * 4 + rr;
                lk32[rl * 10 + wn * 2]     = k1;
                lk32[rl * 10 + wn * 2 + 1] = k2;
            }
        }
    }
    __syncthreads();
    if (tid < 256) {
        unsigned a1 = lk32[tid * 10], a2 = lk32[tid * 10 + 1];
#pragma unroll
        for (int p = 1; p < 4; ++p)
            top2_merge32(a1, a2, lk32[tid * 10 + p * 2], lk32[tid * 10 + p * 2 + 1]);
        size_t base = (size_t)(mt * 256 + tid) * 32 + nt * 2;
        rk2[base] = a1;
        rk2[base + 1] = a2;
    }
}

// ---------------- refine: np-fp32-semantics over approx-top-4 of 32 candidates;
// winner z_q via LDS broadcast from the winning group's registers. NO fences.
__global__ __launch_bounds__(256) void refine_k(
    const unsigned* __restrict__ rk2,
    const float* __restrict__ embed, const float* __restrict__ z,
    const float* __restrict__ C32,
    float* __restrict__ out, unsigned* __restrict__ counts,
    double* __restrict__ rloss) {
    __shared__ float zs[4][512];
    __shared__ float zqs[4][512];
    const int wv = threadIdx.x >> 6, t = threadIdx.x & 63;
    const int r = blockIdx.x * 4 + wv;
    const float4* zp = (const float4*)(z + (size_t)r * DIMV);
    float4 za = zp[t * 2], zb = zp[t * 2 + 1];
    ((float4*)zs[wv])[t * 2] = za;
    ((float4*)zs[wv])[t * 2 + 1] = zb;
    __syncthreads();

    // np-exact A = np.sum(z*z, axis=1)
    float A32 = np_pairwise_sq(zs[wv], t);

    // rebuild unique u64 work keys (biased-dist24 | global col) from u32 keys
    unsigned long long key = ~0ull;
    if (t < 32) {
        unsigned kraw = rk2[(size_t)r * 32 + t];
        unsigned col = (unsigned)(t >> 1) * 256u + (kraw & 255u);
        key = ((unsigned long long)(kraw & 0xFFFFFF00u) << 32) | col;
    }

    // extract approx top-4; 16-lane group g keeps candidate #g
    const int g = t >> 4, j = t & 15;
    unsigned mycand = 0;
#pragma unroll
    for (int c = 0; c < 4; ++c) {
        unsigned long long m = key;
#pragma unroll
        for (int d = 1; d < 64; d <<= 1) {
            unsigned long long o = __shfl_xor(m, d, 64);
            m = o < m ? o : m;
        }
        if (c == g) mycand = (unsigned)(m & 0xFFFFFFFFull);
        if (key == m) key = ~0ull;   // keys unique (global col in low bits)
    }

    // parallel scoring: group g computes B = z . e_mycand in fp64; keep e vals
    const float4* ep = (const float4*)(embed + (size_t)mycand * DIMV);
    float4 ev[8];
    double s = 0.0;
#pragma unroll
    for (int it = 0; it < 8; ++it) {
        float4 e4 = ep[j + it * 16];
        ev[it] = e4;
        float4 z4 = ((const float4*)zs[wv])[j + it * 16];
        s += (double)z4.x * e4.x + (double)z4.y * e4.y +
             (double)z4.z * e4.z + (double)z4.w * e4.w;
    }
#pragma unroll
    for (int d = 1; d < 16; d <<= 1) s += __shfl_xor(s, d, 64);   // group sum

    // np rounding grid: d = fl(fl(A - 2B) + C)
    float Bf = (float)s;
    float d32 = (A32 - 2.0f * Bf) + C32[mycand];
    unsigned u = __float_as_uint(d32);
    u = (u & 0x80000000u) ? ~u : (u | 0x80000000u);
    unsigned long long dk = ((unsigned long long)u << 32) | mycand;
#pragma unroll
    for (int d = 16; d < 64; d <<= 1) {                           // cross-group argmin
        unsigned long long o = __shfl_xor(dk, d, 64);
        dk = o < dk ? o : dk;
    }
    const unsigned ibest = (unsigned)(dk & 0xFFFFFFFFull);

    // winner broadcast: winning group's registers -> LDS (candidates unique,
    // exactly one group matches)
    if (mycand == ibest) {
#pragma unroll
        for (int it = 0; it < 8; ++it) ((float4*)zqs[wv])[j + it * 16] = ev[it];
    }
    __syncthreads();

    float4 wa = ((const float4*)zqs[wv])[t * 2];
    float4 wb = ((const float4*)zqs[wv])[t * 2 + 1];
    float4* op = (float4*)(out + (size_t)r * DIMV);
    op[t * 2] = wa;
    op[t * 2 + 1] = wb;
    double dx0 = (double)za.x - wa.x, dx1 = (double)za.y - wa.y;
    double dx2 = (double)za.z - wa.z, dx3 = (double)za.w - wa.w;
    double dx4 = (double)zb.x - wb.x, dx5 = (double)zb.y - wb.y;
    double dx6 = (double)zb.z - wb.z, dx7 = (double)zb.w - wb.w;
    double ls = dx0 * dx0 + dx1 * dx1 + dx2 * dx2 + dx3 * dx3 +
                dx4 * dx4 + dx5 * dx5 + dx6 * dx6 + dx7 * dx7;
#pragma unroll
    for (int d = 1; d < 64; d <<= 1) ls += __shfl_xor(ls, d, 64);
    if (t == 0) {
        out[IDX_OFF + r] = (float)ibest;
        rloss[r] = ls;
        atomicAdd(&counts[ibest], 1u);
    }
}

// ---------------- scalars: vq_loss (reduce rloss) + perplexity. Separate
// dispatch: the kernel boundary is the (free) device-scope coherence point —
// r9 showed per-block __threadfence costs ~500us here.
__global__ __launch_bounds__(1024) void scalars_k(
    const unsigned* __restrict__ counts,
    const double* __restrict__ rloss, float* __restrict__ out) {
    int t = threadIdx.x;   // 1024
    double ls = 0.0;
    for (int i = t; i < NTOK; i += 1024) ls += rloss[i];
#pragma unroll
    for (int d = 1; d < 64; d <<= 1) ls += __shfl_xor(ls, d, 64);
    float s = 0.0f;
    for (int i = t; i < KCODE; i += 1024) {
        float p = (float)counts[i] * (1.0f / (float)NTOK);
        s += p * logf(p + 1e-10f);
    }
#pragma unroll
    for (int d = 1; d < 64; d <<= 1) s += __shfl_xor(s, d, 64);
    __shared__ float red[16];
    __shared__ double redd[16];
    if ((t & 63) == 0) { red[t >> 6] = s; redd[t >> 6] = ls; }
    __syncthreads();
    if (t == 0) {
        float stot = 0.0f;
        double ltot = 0.0;
#pragma unroll
        for (int i = 0; i < 16; ++i) { stot += red[i]; ltot += redd[i]; }
        out[PERPO] = expf(-stot);
        out[LOSSO] = 0.25f * (float)(ltot * (1.0 / (double)(NTOK * DIMV)));
    }
}

extern "C" void kernel_launch(void* const* d_in, const int* in_sizes, int n_in,
                              void* d_out, int out_size, void* d_ws, size_t ws_size,
                              hipStream_t stream) {
    const float* z     = (const float*)d_in[0];
    const float* embed = (const float*)d_in[1];
    float* out = (float*)d_out;
    char* ws = (char*)d_ws;

    _Float16* A2 = (_Float16*)(ws + A2_OFF);
    _Float16* B2 = (_Float16*)(ws + B2_OFF);
    float* C32 = (float*)(ws + EN_OFF);
    unsigned* rk2 = (unsigned*)(ws + RK_OFF);
    unsigned* counts = (unsigned*)(ws + CNT_OFF);
    double* rloss = (double*)(ws + RLOSS_OFF);

    prep_k<<<5120, 256, 0, stream>>>(z, embed, A2, B2, C32, counts);
    gemm_top2_k<<<dim3(16, 64), 512, 0, stream>>>(A2, B2, C32, rk2);
    refine_k<<<NTOK / 4, 256, 0, stream>>>(rk2, embed, z, C32, out, counts, rloss);
    scalars_k<<<1, 1024, 0, stream>>>(counts, rloss, out);
}

// Round 4
// 218.264 us; speedup vs baseline: 1.0146x; 1.0016x over previous
//
#include <hip/hip_runtime.h>
#include <cstdint>
#include <cstddef>

typedef _Float16 f16x8 __attribute__((ext_vector_type(8)));
typedef float f32x4 __attribute__((ext_vector_type(4)));

#define NTOK 16384
#define DIMV 512
#define KCODE 4096

// output layout (float32): z_q_st | indices | vq_loss | perplexity
#define IDX_OFF (NTOK * DIMV)
#define LOSSO   (IDX_OFF + NTOK)
#define PERPO   (LOSSO + 1)

// workspace layout (rk2 now lives in d_out's z_q region -- see gemm epilogue)
static const size_t A2_OFF = 0;                                   // fp16 256*z   [NTOK][512]
static const size_t B2_OFF = A2_OFF + (size_t)NTOK * DIMV * 2;    // fp16 256*e   [KCODE][512]
static const size_t EN_OFF = B2_OFF + (size_t)KCODE * DIMV * 2;   // f32 C32 = np-pairwise ||e||^2
static const size_t CNT_OFF = EN_OFF + (size_t)KCODE * 4;         // u32 [KCODE]
static const size_t RLOSS_OFF = CNT_OFF + (size_t)KCODE * 4;      // f64 [NTOK] per-row loss

// fp32 square with contraction barrier (mimic numpy's separate multiply+add)
__device__ __forceinline__ float sqf(float v) {
    float p = v * v;
    asm volatile("" : "+v"(p));
    return p;
}

// numpy pairwise sum of squares of a 512-elem LDS row (verified r3-r8).
__device__ __forceinline__ float np_pairwise_sq(const float* xs, int t) {
    float accp = 0.0f;
    if (t < 32) {
        const float* blk = xs + (t >> 3) * 128;
        int j = t & 7;
        float rj = sqf(blk[j]);
#pragma unroll
        for (int tt = 1; tt < 16; ++tt) rj += sqf(blk[tt * 8 + j]);
        accp = rj;
    }
#pragma unroll
    for (int d = 1; d <= 16; d <<= 1) accp += __shfl_xor(accp, d, 64);
    return __shfl(accp, 0, 64);
}

// ---------------- fused prep: z->fp16, embed->fp16 + C32 + zero counts
__global__ void prep_k(const float* __restrict__ z, const float* __restrict__ e,
                       _Float16* __restrict__ A2, _Float16* __restrict__ B2,
                       float* __restrict__ C32, unsigned* __restrict__ counts) {
    __shared__ float es[4][512];
    const int b = blockIdx.x;
    if (b < 4096) {                       // z: 4 rows per block
        int t = b * 256 + threadIdx.x;
        int n = t >> 6;
        int dc = (t & 63) << 3;
        const float* zp = z + (size_t)n * DIMV + dc;
        float4 v0 = ((const float4*)zp)[0];
        float4 v1 = ((const float4*)zp)[1];
        float vs[8] = {v0.x, v0.y, v0.z, v0.w, v1.x, v1.y, v1.z, v1.w};
        f16x8 hi;
#pragma unroll
        for (int i = 0; i < 8; ++i) hi[i] = (_Float16)(vs[i] * 256.0f);
        *(f16x8*)(A2 + (size_t)n * DIMV + dc) = hi;
    } else {                              // embed: 4 rows per block, 1 wave/row
        const int wv = threadIdx.x >> 6, t = threadIdx.x & 63;
        const int k = (b - 4096) * 4 + wv;
        const float* ep = e + (size_t)k * DIMV + t * 8;
        float4 v0 = ((const float4*)ep)[0];
        float4 v1 = ((const float4*)ep)[1];
        ((float4*)es[wv])[t * 2] = v0;
        ((float4*)es[wv])[t * 2 + 1] = v1;
        float vs[8] = {v0.x, v0.y, v0.z, v0.w, v1.x, v1.y, v1.z, v1.w};
        f16x8 hi;
#pragma unroll
        for (int i = 0; i < 8; ++i) hi[i] = (_Float16)(vs[i] * 256.0f);
        *(f16x8*)(B2 + (size_t)k * DIMV + t * 8) = hi;
        float c = np_pairwise_sq(es[wv], t);
        if (t == 0) C32[k] = c;
        if (threadIdx.x < 4) counts[(b - 4096) * 4 + threadIdx.x] = 0u;
    }
}

// ---------------- async global->LDS 16B
typedef uint32_t __attribute__((address_space(1))) gas_u32;
typedef uint32_t __attribute__((address_space(3))) las_u32;
__device__ __forceinline__ void g2l16(const _Float16* g, _Float16* l) {
    __builtin_amdgcn_global_load_lds((const gas_u32*)(uintptr_t)g,
                                     (las_u32*)(uint32_t)(uintptr_t)l, 16, 0, 0);
}

__device__ __forceinline__ void top2_merge32(unsigned& k1, unsigned& k2,
                                             unsigned o1, unsigned o2) {
    unsigned n1 = k1 < o1 ? k1 : o1;
    unsigned mx = k1 < o1 ? o1 : k1;
    unsigned n2 = k2 < o2 ? k2 : o2;
    k1 = n1;
    k2 = mx < n2 ? mx : n2;
}

// DPP row_shr top-2 reduction stage (pure VALU, no DS pipe).
// row_shr:N moves lane i-N -> lane i: merge ACCUMULATES TOWARD LANE 15 of each
// 16-lane row; out-of-row sources take old = -1 (identity for min).
#define DPP_TOP2(CTRL)                                                                     \
    {                                                                                      \
        unsigned o1 = (unsigned)__builtin_amdgcn_update_dpp(-1, (int)k1, CTRL, 0xF, 0xF, false); \
        unsigned o2 = (unsigned)__builtin_amdgcn_update_dpp(-1, (int)k2, CTRL, 0xF, 0xF, false); \
        top2_merge32(k1, k2, o1, o2);                                                      \
    }

// ---------------- GEMM (K=512 fp16, 128x128 tile, 4 waves) + per-tile top-2.
// r0-proven m97 structure (2 barriers/K-tile, implicit wave-level overlap at
// multiple blocks/CU); tile re-sized per m103's measured tile-space at this
// structure (128^2 = 912 TF > 128x256 = 823 TF). Staging swizzle verbatim from
// r0 (measured 0 bank conflicts). Top-2 keys for the 32 code-tiles of 128 are
// written into d_out's z_q region (row r words [0,64)) -- refine reads them
// before overwriting the row; zero workspace growth.
__global__ __launch_bounds__(256) void gemm_top2_k(
    const _Float16* __restrict__ A2, const _Float16* __restrict__ B2,
    const float* __restrict__ C32, unsigned* __restrict__ rk2) {
    __shared__ _Float16 lA[128 * 64];   // 16 KB (reused for epilogue merge)
    __shared__ _Float16 lB[128 * 64];   // 16 KB
    const int nt = blockIdx.x;     // 32 code tiles of 128
    const int mt = blockIdx.y;     // 128 row tiles of 128
    const int tid = threadIdx.x;
    const int w = tid >> 6, l = tid & 63;
    const int wm = w & 1, wn = w >> 1;   // 2 x 2 wave grid, each wave 64x64

    // staging: lane l loads 16B; row = l>>3, chunk = l&7, XOR-swizzled source
    const int srow = l >> 3, schunk = l & 7;
    const int gch = (schunk ^ srow) << 3;
    const _Float16* aG = A2 + (size_t)(mt * 128 + w * 32 + srow) * DIMV + gch;
    const _Float16* bG = B2 + (size_t)(nt * 128 + w * 32 + srow) * DIMV + gch;
    _Float16* aL = &lA[(w * 32) * 64];
    _Float16* bL = &lB[(w * 32) * 64];

    const int lane15 = l & 15, q = l >> 4, sx = l & 7;
    const int aRow = (wm * 64 + lane15) * 64;
    const int bRow = (wn * 64 + lane15) * 64;

    f32x4 acc[4][4] = {};

    for (int kt = 0; kt < 8; ++kt) {
        const _Float16* ag = aG + kt * 64;
        const _Float16* bg = bG + kt * 64;
#pragma unroll
        for (int r = 0; r < 4; ++r) g2l16(ag + (size_t)r * 8 * DIMV, aL + r * 512);
#pragma unroll
        for (int r = 0; r < 4; ++r) g2l16(bg + (size_t)r * 8 * DIMV, bL + r * 512);
        __syncthreads();

#pragma unroll
        for (int kk2 = 0; kk2 < 2; ++kk2) {
            f16x8 af[4], bf[4];
            const int ch = ((kk2 * 4 + q) ^ sx) << 3;
#pragma unroll
            for (int i = 0; i < 4; ++i) {
                af[i] = *(const f16x8*)&lA[aRow + i * 1024 + ch];
                bf[i] = *(const f16x8*)&lB[bRow + i * 1024 + ch];
            }
#pragma unroll
            for (int i = 0; i < 4; ++i)
#pragma unroll
                for (int j = 0; j < 4; ++j)
                    acc[i][j] = __builtin_amdgcn_mfma_f32_16x16x32_f16(af[i], bf[j], acc[i][j], 0, 0, 0);
        }
        __syncthreads();
    }

    // epilogue: dist = 65536*C32 - 2*acc + BIAS (4e6 > |range|): positive => raw
    // IEEE bits monotone; truncate to 24 bits, pack tile-col in low byte.
    unsigned* lk32 = (unsigned*)lA;    // [128 rows][stride 5]: 2 wn-slots x 2
    const int colL = wn * 64 + lane15;               // 0..127 within tile
    float envals[4];
#pragma unroll
    for (int j = 0; j < 4; ++j) envals[j] = C32[nt * 128 + colL + j * 16] * 65536.0f + 4.0e6f;

#pragma unroll
    for (int i = 0; i < 4; ++i) {
#pragma unroll
        for (int rr = 0; rr < 4; ++rr) {
            unsigned k1 = 0xFFFFFFFFu, k2 = 0xFFFFFFFFu;
#pragma unroll
            for (int j = 0; j < 4; ++j) {
                float dist = envals[j] - 2.0f * acc[i][j][rr];
                unsigned key = (__float_as_uint(dist) & 0xFFFFFF00u) | (unsigned)(colL + j * 16);
                if (key < k1) { k2 = k1; k1 = key; } else if (key < k2) k2 = key;
            }
            DPP_TOP2(0x118)   // row_shr:8
            DPP_TOP2(0x114)   // row_shr:4
            DPP_TOP2(0x112)   // row_shr:2
            DPP_TOP2(0x111)   // row_shr:1  -> LANE 15 of each 16 has row top-2
            if (lane15 == 15) {
                int rl = wm * 64 + i * 16 + q * 4 + rr;
                lk32[rl * 5 + wn * 2]     = k1;
                lk32[rl * 5 + wn * 2 + 1] = k2;
            }
        }
    }
    __syncthreads();
    if (tid < 128) {
        unsigned a1 = lk32[tid * 5], a2 = lk32[tid * 5 + 1];
        top2_merge32(a1, a2, lk32[tid * 5 + 2], lk32[tid * 5 + 3]);
        // keys live in out's z_q row (512 f32): words [0,64) of row mt*128+tid
        size_t base = (size_t)(mt * 128 + tid) * 512 + nt * 2;
        rk2[base] = a1;
        rk2[base + 1] = a2;
    }
}

// ---------------- refine: np-fp32-semantics over approx-top-4 of 64 candidates
// (top-2 per 128-code tile, a superset of the old per-256 top-2); winner z_q via
// LDS broadcast from the winning group's registers. Keys are read from the out
// row itself (written by gemm) BEFORE the row is overwritten. NO fences.
__global__ __launch_bounds__(256) void refine_k(
    const float* __restrict__ embed, const float* __restrict__ z,
    const float* __restrict__ C32,
    float* __restrict__ out, unsigned* __restrict__ counts,
    double* __restrict__ rloss) {
    __shared__ float zs[4][512];
    __shared__ float zqs[4][512];
    const int wv = threadIdx.x >> 6, t = threadIdx.x & 63;
    const int r = blockIdx.x * 4 + wv;

    // read this row's 64 candidate keys FIRST (they occupy out row words [0,64))
    unsigned kraw = ((const unsigned*)out)[(size_t)r * 512 + t];

    const float4* zp = (const float4*)(z + (size_t)r * DIMV);
    float4 za = zp[t * 2], zb = zp[t * 2 + 1];
    ((float4*)zs[wv])[t * 2] = za;
    ((float4*)zs[wv])[t * 2 + 1] = zb;
    __syncthreads();

    // np-exact A = np.sum(z*z, axis=1)
    float A32 = np_pairwise_sq(zs[wv], t);

    // rebuild unique u64 work keys (biased-dist24 | global col) from u32 keys:
    // lane t holds tile t>>1's {first,second} key; col = tile*128 + local col.
    unsigned col = (unsigned)(t >> 1) * 128u + (kraw & 255u);
    unsigned long long key = ((unsigned long long)(kraw & 0xFFFFFF00u) << 32) | col;

    // extract approx top-4; 16-lane group g keeps candidate #g
    const int g = t >> 4, j = t & 15;
    unsigned mycand = 0;
#pragma unroll
    for (int c = 0; c < 4; ++c) {
        unsigned long long m = key;
#pragma unroll
        for (int d = 1; d < 64; d <<= 1) {
            unsigned long long o = __shfl_xor(m, d, 64);
            m = o < m ? o : m;
        }
        if (c == g) mycand = (unsigned)(m & 0xFFFFFFFFull);
        if (key == m) key = ~0ull;   // keys unique (global col in low bits)
    }

    // parallel scoring: group g computes B = z . e_mycand in fp64; keep e vals
    const float4* ep = (const float4*)(embed + (size_t)mycand * DIMV);
    float4 ev[8];
    double s = 0.0;
#pragma unroll
    for (int it = 0; it < 8; ++it) {
        float4 e4 = ep[j + it * 16];
        ev[it] = e4;
        float4 z4 = ((const float4*)zs[wv])[j + it * 16];
        s += (double)z4.x * e4.x + (double)z4.y * e4.y +
             (double)z4.z * e4.z + (double)z4.w * e4.w;
    }
#pragma unroll
    for (int d = 1; d < 16; d <<= 1) s += __shfl_xor(s, d, 64);   // group sum

    // np rounding grid: d = fl(fl(A - 2B) + C)
    float Bf = (float)s;
    float d32 = (A32 - 2.0f * Bf) + C32[mycand];
    unsigned u = __float_as_uint(d32);
    u = (u & 0x80000000u) ? ~u : (u | 0x80000000u);
    unsigned long long dk = ((unsigned long long)u << 32) | mycand;
#pragma unroll
    for (int d = 16; d < 64; d <<= 1) {                           // cross-group argmin
        unsigned long long o = __shfl_xor(dk, d, 64);
        dk = o < dk ? o : dk;
    }
    const unsigned ibest = (unsigned)(dk & 0xFFFFFFFFull);

    // winner broadcast: winning group's registers -> LDS (candidates unique,
    // exactly one group matches)
    if (mycand == ibest) {
#pragma unroll
        for (int it = 0; it < 8; ++it) ((float4*)zqs[wv])[j + it * 16] = ev[it];
    }
    __syncthreads();

    float4 wa = ((const float4*)zqs[wv])[t * 2];
    float4 wb = ((const float4*)zqs[wv])[t * 2 + 1];
    float4* op = (float4*)(out + (size_t)r * DIMV);
    op[t * 2] = wa;
    op[t * 2 + 1] = wb;
    double dx0 = (double)za.x - wa.x, dx1 = (double)za.y - wa.y;
    double dx2 = (double)za.z - wa.z, dx3 = (double)za.w - wa.w;
    double dx4 = (double)zb.x - wb.x, dx5 = (double)zb.y - wb.y;
    double dx6 = (double)zb.z - wb.z, dx7 = (double)zb.w - wb.w;
    double ls = dx0 * dx0 + dx1 * dx1 + dx2 * dx2 + dx3 * dx3 +
                dx4 * dx4 + dx5 * dx5 + dx6 * dx6 + dx7 * dx7;
#pragma unroll
    for (int d = 1; d < 64; d <<= 1) ls += __shfl_xor(ls, d, 64);
    if (t == 0) {
        out[IDX_OFF + r] = (float)ibest;
        rloss[r] = ls;
        atomicAdd(&counts[ibest], 1u);
    }
}

// ---------------- scalars: vq_loss (reduce rloss) + perplexity. Separate
// dispatch: the kernel boundary is the (free) device-scope coherence point —
// r9 showed per-block __threadfence costs ~500us here.
__global__ __launch_bounds__(1024) void scalars_k(
    const unsigned* __restrict__ counts,
    const double* __restrict__ rloss, float* __restrict__ out) {
    int t = threadIdx.x;   // 1024
    double ls = 0.0;
    for (int i = t; i < NTOK; i += 1024) ls += rloss[i];
#pragma unroll
    for (int d = 1; d < 64; d <<= 1) ls += __shfl_xor(ls, d, 64);
    float s = 0.0f;
    for (int i = t; i < KCODE; i += 1024) {
        float p = (float)counts[i] * (1.0f / (float)NTOK);
        s += p * logf(p + 1e-10f);
    }
#pragma unroll
    for (int d = 1; d < 64; d <<= 1) s += __shfl_xor(s, d, 64);
    __shared__ float red[16];
    __shared__ double redd[16];
    if ((t & 63) == 0) { red[t >> 6] = s; redd[t >> 6] = ls; }
    __syncthreads();
    if (t == 0) {
        float stot = 0.0f;
        double ltot = 0.0;
#pragma unroll
        for (int i = 0; i < 16; ++i) { stot += red[i]; ltot += redd[i]; }
        out[PERPO] = expf(-stot);
        out[LOSSO] = 0.25f * (float)(ltot * (1.0 / (double)(NTOK * DIMV)));
    }
}

extern "C" void kernel_launch(void* const* d_in, const int* in_sizes, int n_in,
                              void* d_out, int out_size, void* d_ws, size_t ws_size,
                              hipStream_t stream) {
    const float* z     = (const float*)d_in[0];
    const float* embed = (const float*)d_in[1];
    float* out = (float*)d_out;
    char* ws = (char*)d_ws;

    _Float16* A2 = (_Float16*)(ws + A2_OFF);
    _Float16* B2 = (_Float16*)(ws + B2_OFF);
    float* C32 = (float*)(ws + EN_OFF);
    unsigned* counts = (unsigned*)(ws + CNT_OFF);
    double* rloss = (double*)(ws + RLOSS_OFF);

    prep_k<<<5120, 256, 0, stream>>>(z, embed, A2, B2, C32, counts);
    gemm_top2_k<<<dim3(32, 128), 256, 0, stream>>>(A2, B2, C32, (unsigned*)out);
    refine_k<<<NTOK / 4, 256, 0, stream>>>(embed, z, C32, out, counts, rloss);
    scalars_k<<<1, 1024, 0, stream>>>(counts, rloss, out);
}

// Round 6
// 212.429 us; speedup vs baseline: 1.0424x; 1.0275x over previous
//
#include <hip/hip_runtime.h>
#include <cstdint>
#include <cstddef>

typedef _Float16 f16x8 __attribute__((ext_vector_type(8)));
typedef float f32x4 __attribute__((ext_vector_type(4)));

#define NTOK 16384
#define DIMV 512
#define KCODE 4096

// output layout (float32): z_q_st | indices | vq_loss | perplexity
#define IDX_OFF (NTOK * DIMV)
#define LOSSO   (IDX_OFF + NTOK)
#define PERPO   (LOSSO + 1)

// workspace layout
static const size_t A2_OFF = 0;                                   // fp16 256*z   [NTOK][512]
static const size_t B2_OFF = A2_OFF + (size_t)NTOK * DIMV * 2;    // fp16 256*e   [KCODE][512]
static const size_t EN_OFF = B2_OFF + (size_t)KCODE * DIMV * 2;   // f32 C32 = np-pairwise ||e||^2
static const size_t RK_OFF = EN_OFF + (size_t)KCODE * 4;          // u32 [NTOK][16 tiles][2] top-2 keys
static const size_t CNT_OFF = RK_OFF + (size_t)NTOK * 32 * 4;     // u32 [KCODE]
static const size_t RLOSS_OFF = CNT_OFF + (size_t)KCODE * 4;      // f64 [NTOK] per-row loss

// fp32 square with contraction barrier (mimic numpy's separate multiply+add)
__device__ __forceinline__ float sqf(float v) {
    float p = v * v;
    asm volatile("" : "+v"(p));
    return p;
}

// numpy pairwise sum of squares of a 512-elem LDS row (verified r3-r8).
__device__ __forceinline__ float np_pairwise_sq(const float* xs, int t) {
    float accp = 0.0f;
    if (t < 32) {
        const float* blk = xs + (t >> 3) * 128;
        int j = t & 7;
        float rj = sqf(blk[j]);
#pragma unroll
        for (int tt = 1; tt < 16; ++tt) rj += sqf(blk[tt * 8 + j]);
        accp = rj;
    }
#pragma unroll
    for (int d = 1; d <= 16; d <<= 1) accp += __shfl_xor(accp, d, 64);
    return __shfl(accp, 0, 64);
}

// ---------------- fused prep: z->fp16, embed->fp16 + C32 + zero counts
__global__ void prep_k(const float* __restrict__ z, const float* __restrict__ e,
                       _Float16* __restrict__ A2, _Float16* __restrict__ B2,
                       float* __restrict__ C32, unsigned* __restrict__ counts) {
    __shared__ float es[4][512];
    const int b = blockIdx.x;
    if (b < 4096) {                       // z: 4 rows per block
        int t = b * 256 + threadIdx.x;
        int n = t >> 6;
        int dc = (t & 63) << 3;
        const float* zp = z + (size_t)n * DIMV + dc;
        float4 v0 = ((const float4*)zp)[0];
        float4 v1 = ((const float4*)zp)[1];
        float vs[8] = {v0.x, v0.y, v0.z, v0.w, v1.x, v1.y, v1.z, v1.w};
        f16x8 hi;
#pragma unroll
        for (int i = 0; i < 8; ++i) hi[i] = (_Float16)(vs[i] * 256.0f);
        *(f16x8*)(A2 + (size_t)n * DIMV + dc) = hi;
    } else {                              // embed: 4 rows per block, 1 wave/row
        const int wv = threadIdx.x >> 6, t = threadIdx.x & 63;
        const int k = (b - 4096) * 4 + wv;
        const float* ep = e + (size_t)k * DIMV + t * 8;
        float4 v0 = ((const float4*)ep)[0];
        float4 v1 = ((const float4*)ep)[1];
        ((float4*)es[wv])[t * 2] = v0;
        ((float4*)es[wv])[t * 2 + 1] = v1;
        float vs[8] = {v0.x, v0.y, v0.z, v0.w, v1.x, v1.y, v1.z, v1.w};
        f16x8 hi;
#pragma unroll
        for (int i = 0; i < 8; ++i) hi[i] = (_Float16)(vs[i] * 256.0f);
        *(f16x8*)(B2 + (size_t)k * DIMV + t * 8) = hi;
        float c = np_pairwise_sq(es[wv], t);
        if (t == 0) C32[k] = c;
        if (threadIdx.x < 4) counts[(b - 4096) * 4 + threadIdx.x] = 0u;
    }
}

// ---------------- async global->LDS 16B
typedef uint32_t __attribute__((address_space(1))) gas_u32;
typedef uint32_t __attribute__((address_space(3))) las_u32;
__device__ __forceinline__ void g2l16(const _Float16* g, _Float16* l) {
    __builtin_amdgcn_global_load_lds((const gas_u32*)(uintptr_t)g,
                                     (las_u32*)(uint32_t)(uintptr_t)l, 16, 0, 0);
}

__device__ __forceinline__ void top2_merge32(unsigned& k1, unsigned& k2,
                                             unsigned o1, unsigned o2) {
    unsigned n1 = k1 < o1 ? k1 : o1;
    unsigned mx = k1 < o1 ? o1 : k1;
    unsigned n2 = k2 < o2 ? k2 : o2;
    k1 = n1;
    k2 = mx < n2 ? mx : n2;
}

// DPP row_shr top-2 reduction stage (pure VALU, no DS pipe).
// row_shr:N moves lane i-N -> lane i: merge ACCUMULATES TOWARD LANE 15 of each
// 16-lane row; out-of-row sources take old = -1 (identity for min).
#define DPP_TOP2(CTRL)                                                                     \
    {                                                                                      \
        unsigned o1 = (unsigned)__builtin_amdgcn_update_dpp(-1, (int)k1, CTRL, 0xF, 0xF, false); \
        unsigned o2 = (unsigned)__builtin_amdgcn_update_dpp(-1, (int)k2, CTRL, 0xF, 0xF, false); \
        top2_merge32(k1, k2, o1, o2);                                                      \
    }

// ---------------- GEMM (K=512 fp16, 128x256 tile, 8 waves) + per-tile top-2
// r0-verbatim structure (proven 81.7us full-grid). Split into two half-row
// dispatches via mtb so each runs ~41us: surfaces any slower non-gemm kernel
// in rocprof's top-5 and measures per-dispatch launch overhead (total delta).
__global__ __launch_bounds__(512) void gemm_top2_k(
    const _Float16* __restrict__ A2, const _Float16* __restrict__ B2,
    const float* __restrict__ C32, unsigned* __restrict__ rk2, int mtb) {
    __shared__ _Float16 lA[128 * 64];   // 16 KB (reused for epilogue merge)
    __shared__ _Float16 lB[256 * 64];   // 32 KB
    const int nt = blockIdx.x;     // 16 code tiles of 256
    const int mt = mtb + blockIdx.y;   // row tiles of 128
    const int tid = threadIdx.x;
    const int w = tid >> 6, l = tid & 63;
    const int wm = w & 1, wn = w >> 1;   // 2 x 4 wave grid, each wave 64x64

    // staging: lane l loads 16B; row = l>>3, chunk = l&7, XOR-swizzled source
    const int srow = l >> 3, schunk = l & 7;
    const int gch = (schunk ^ srow) << 3;
    const _Float16* aG = A2 + (size_t)(mt * 128 + w * 16 + srow) * DIMV + gch;
    const _Float16* bG = B2 + (size_t)(nt * 256 + w * 32 + srow) * DIMV + gch;
    _Float16* aL = &lA[(w * 16) * 64];
    _Float16* bL = &lB[(w * 32) * 64];

    const int lane15 = l & 15, q = l >> 4, sx = l & 7;
    const int aRow = (wm * 64 + lane15) * 64;
    const int bRow = (wn * 64 + lane15) * 64;

    f32x4 acc[4][4] = {};

    for (int kt = 0; kt < 8; ++kt) {
        const _Float16* ag = aG + kt * 64;
        const _Float16* bg = bG + kt * 64;
#pragma unroll
        for (int r = 0; r < 2; ++r) g2l16(ag + (size_t)r * 8 * DIMV, aL + r * 512);
#pragma unroll
        for (int r = 0; r < 4; ++r) g2l16(bg + (size_t)r * 8 * DIMV, bL + r * 512);
        __syncthreads();

#pragma unroll
        for (int kk2 = 0; kk2 < 2; ++kk2) {
            f16x8 af[4], bf[4];
            const int ch = ((kk2 * 4 + q) ^ sx) << 3;
#pragma unroll
            for (int i = 0; i < 4; ++i) {
                af[i] = *(const f16x8*)&lA[aRow + i * 1024 + ch];
                bf[i] = *(const f16x8*)&lB[bRow + i * 1024 + ch];
            }
#pragma unroll
            for (int i = 0; i < 4; ++i)
#pragma unroll
                for (int j = 0; j < 4; ++j)
                    acc[i][j] = __builtin_amdgcn_mfma_f32_16x16x32_f16(af[i], bf[j], acc[i][j], 0, 0, 0);
        }
        __syncthreads();
    }

    // epilogue: dist = 65536*C32 - 2*acc + BIAS (4e6 > |range|): positive => raw
    // IEEE bits monotone; truncate to 24 bits, pack tile-col in low byte.
    unsigned* lk32 = (unsigned*)lA;    // [128 rows][stride 10]: 4 wn-slots x 2
    const int colL = wn * 64 + lane15;               // 0..255
    float envals[4];
#pragma unroll
    for (int j = 0; j < 4; ++j) envals[j] = C32[nt * 256 + colL + j * 16] * 65536.0f + 4.0e6f;

#pragma unroll
    for (int i = 0; i < 4; ++i) {
#pragma unroll
        for (int rr = 0; rr < 4; ++rr) {
            unsigned k1 = 0xFFFFFFFFu, k2 = 0xFFFFFFFFu;
#pragma unroll
            for (int j = 0; j < 4; ++j) {
                float dist = envals[j] - 2.0f * acc[i][j][rr];
                unsigned key = (__float_as_uint(dist) & 0xFFFFFF00u) | (unsigned)(colL + j * 16);
                if (key < k1) { k2 = k1; k1 = key; } else if (key < k2) k2 = key;
            }
            DPP_TOP2(0x118)   // row_shr:8
            DPP_TOP2(0x114)   // row_shr:4
            DPP_TOP2(0x112)   // row_shr:2
            DPP_TOP2(0x111)   // row_shr:1  -> LANE 15 of each 16 has row top-2
            if (lane15 == 15) {
                int rl = wm * 64 + i * 16 + q * 4 + rr;
                lk32[rl * 10 + wn * 2]     = k1;
                lk32[rl * 10 + wn * 2 + 1] = k2;
            }
        }
    }
    __syncthreads();
    if (tid < 128) {
        unsigned a1 = lk32[tid * 10], a2 = lk32[tid * 10 + 1];
#pragma unroll
        for (int p = 1; p < 4; ++p)
            top2_merge32(a1, a2, lk32[tid * 10 + p * 2], lk32[tid * 10 + p * 2 + 1]);
        size_t base = (size_t)(mt * 128 + tid) * 32 + nt * 2;
        rk2[base] = a1;
        rk2[base + 1] = a2;
    }
}

// ---------------- refine: np-fp32-semantics over approx-top-4 of 32 candidates;
// winner z_q via LDS broadcast from the winning group's registers. NO fences.
__global__ __launch_bounds__(256) void refine_k(
    const unsigned* __restrict__ rk2,
    const float* __restrict__ embed, const float* __restrict__ z,
    const float* __restrict__ C32,
    float* __restrict__ out, unsigned* __restrict__ counts,
    double* __restrict__ rloss) {
    __shared__ float zs[4][512];
    __shared__ float zqs[4][512];
    const int wv = threadIdx.x >> 6, t = threadIdx.x & 63;
    const int r = blockIdx.x * 4 + wv;
    const float4* zp = (const float4*)(z + (size_t)r * DIMV);
    float4 za = zp[t * 2], zb = zp[t * 2 + 1];
    ((float4*)zs[wv])[t * 2] = za;
    ((float4*)zs[wv])[t * 2 + 1] = zb;
    __syncthreads();

    // np-exact A = np.sum(z*z, axis=1)
    float A32 = np_pairwise_sq(zs[wv], t);

    // rebuild unique u64 work keys (biased-dist24 | global col) from u32 keys
    unsigned long long key = ~0ull;
    if (t < 32) {
        unsigned kraw = rk2[(size_t)r * 32 + t];
        unsigned col = (unsigned)(t >> 1) * 256u + (kraw & 255u);
        key = ((unsigned long long)(kraw & 0xFFFFFF00u) << 32) | col;
    }

    // extract approx top-4; 16-lane group g keeps candidate #g
    const int g = t >> 4, j = t & 15;
    unsigned mycand = 0;
#pragma unroll
    for (int c = 0; c < 4; ++c) {
        unsigned long long m = key;
#pragma unroll
        for (int d = 1; d < 64; d <<= 1) {
            unsigned long long o = __shfl_xor(m, d, 64);
            m = o < m ? o : m;
        }
        if (c == g) mycand = (unsigned)(m & 0xFFFFFFFFull);
        if (key == m) key = ~0ull;   // keys unique (global col in low bits)
    }

    // parallel scoring: group g computes B = z . e_mycand in fp64; keep e vals
    const float4* ep = (const float4*)(embed + (size_t)mycand * DIMV);
    float4 ev[8];
    double s = 0.0;
#pragma unroll
    for (int it = 0; it < 8; ++it) {
        float4 e4 = ep[j + it * 16];
        ev[it] = e4;
        float4 z4 = ((const float4*)zs[wv])[j + it * 16];
        s += (double)z4.x * e4.x + (double)z4.y * e4.y +
             (double)z4.z * e4.z + (double)z4.w * e4.w;
    }
#pragma unroll
    for (int d = 1; d < 16; d <<= 1) s += __shfl_xor(s, d, 64);   // group sum

    // np rounding grid: d = fl(fl(A - 2B) + C)
    float Bf = (float)s;
    float d32 = (A32 - 2.0f * Bf) + C32[mycand];
    unsigned u = __float_as_uint(d32);
    u = (u & 0x80000000u) ? ~u : (u | 0x80000000u);
    unsigned long long dk = ((unsigned long long)u << 32) | mycand;
#pragma unroll
    for (int d = 16; d < 64; d <<= 1) {                           // cross-group argmin
        unsigned long long o = __shfl_xor(dk, d, 64);
        dk = o < dk ? o : dk;
    }
    const unsigned ibest = (unsigned)(dk & 0xFFFFFFFFull);

    // winner broadcast: winning group's registers -> LDS (candidates unique,
    // exactly one group matches)
    if (mycand == ibest) {
#pragma unroll
        for (int it = 0; it < 8; ++it) ((float4*)zqs[wv])[j + it * 16] = ev[it];
    }
    __syncthreads();

    float4 wa = ((const float4*)zqs[wv])[t * 2];
    float4 wb = ((const float4*)zqs[wv])[t * 2 + 1];
    float4* op = (float4*)(out + (size_t)r * DIMV);
    op[t * 2] = wa;
    op[t * 2 + 1] = wb;
    double dx0 = (double)za.x - wa.x, dx1 = (double)za.y - wa.y;
    double dx2 = (double)za.z - wa.z, dx3 = (double)za.w - wa.w;
    double dx4 = (double)zb.x - wb.x, dx5 = (double)zb.y - wb.y;
    double dx6 = (double)zb.z - wb.z, dx7 = (double)zb.w - wb.w;
    double ls = dx0 * dx0 + dx1 * dx1 + dx2 * dx2 + dx3 * dx3 +
                dx4 * dx4 + dx5 * dx5 + dx6 * dx6 + dx7 * dx7;
#pragma unroll
    for (int d = 1; d < 64; d <<= 1) ls += __shfl_xor(ls, d, 64);
    if (t == 0) {
        out[IDX_OFF + r] = (float)ibest;
        rloss[r] = ls;
        atomicAdd(&counts[ibest], 1u);
    }
}

// ---------------- scalars: vq_loss (reduce rloss) + perplexity. Separate
// dispatch: the kernel boundary is the (free) device-scope coherence point —
// r9 showed per-block __threadfence costs ~500us here.
__global__ __launch_bounds__(1024) void scalars_k(
    const unsigned* __restrict__ counts,
    const double* __restrict__ rloss, float* __restrict__ out) {
    int t = threadIdx.x;   // 1024
    double ls = 0.0;
    for (int i = t; i < NTOK; i += 1024) ls += rloss[i];
#pragma unroll
    for (int d = 1; d < 64; d <<= 1) ls += __shfl_xor(ls, d, 64);
    float s = 0.0f;
    for (int i = t; i < KCODE; i += 1024) {
        float p = (float)counts[i] * (1.0f / (float)NTOK);
        s += p * logf(p + 1e-10f);
    }
#pragma unroll
    for (int d = 1; d < 64; d <<= 1) s += __shfl_xor(s, d, 64);
    __shared__ float red[16];
    __shared__ double redd[16];
    if ((t & 63) == 0) { red[t >> 6] = s; redd[t >> 6] = ls; }
    __syncthreads();
    if (t == 0) {
        float stot = 0.0f;
        double ltot = 0.0;
#pragma unroll
        for (int i = 0; i < 16; ++i) { stot += red[i]; ltot += redd[i]; }
        out[PERPO] = expf(-stot);
        out[LOSSO] = 0.25f * (float)(ltot * (1.0 / (double)(NTOK * DIMV)));
    }
}

extern "C" void kernel_launch(void* const* d_in, const int* in_sizes, int n_in,
                              void* d_out, int out_size, void* d_ws, size_t ws_size,
                              hipStream_t stream) {
    const float* z     = (const float*)d_in[0];
    const float* embed = (const float*)d_in[1];
    float* out = (float*)d_out;
    char* ws = (char*)d_ws;

    _Float16* A2 = (_Float16*)(ws + A2_OFF);
    _Float16* B2 = (_Float16*)(ws + B2_OFF);
    float* C32 = (float*)(ws + EN_OFF);
    unsigned* rk2 = (unsigned*)(ws + RK_OFF);
    unsigned* counts = (unsigned*)(ws + CNT_OFF);
    double* rloss = (double*)(ws + RLOSS_OFF);

    prep_k<<<5120, 256, 0, stream>>>(z, embed, A2, B2, C32, counts);
    // r0 gemm split into two half-grids (instrumentation: ~41us each)
    gemm_top2_k<<<dim3(16, 64), 512, 0, stream>>>(A2, B2, C32, rk2, 0);
    gemm_top2_k<<<dim3(16, 64), 512, 0, stream>>>(A2, B2, C32, rk2, 64);
    refine_k<<<NTOK / 4, 256, 0, stream>>>(rk2, embed, z, C32, out, counts, rloss);
    scalars_k<<<1, 1024, 0, stream>>>(counts, rloss, out);
}